// Round 11
// baseline (156.853 us; speedup 1.0000x reference)
//
#include <hip/hip_runtime.h>

typedef unsigned int u32;
typedef __attribute__((ext_vector_type(8))) short short8v;
typedef __attribute__((ext_vector_type(4))) u32 u32x4;
typedef __attribute__((ext_vector_type(4))) float f32x4;

#define NPB 256          // nodes per bucket (sort + aggregation granularity)
#define NPB_SHIFT 8
#define CHP 4096         // edges per chunk (hist + scatter)

// order-preserving float<->uint encoding; enc never returns 0 for real values
__device__ __forceinline__ u32 enc_f32(float f) {
    u32 b = __float_as_uint(f);
    return (b & 0x80000000u) ? ~b : (b | 0x80000000u);
}
__device__ __forceinline__ float dec_f32(u32 u) {
    u32 b = (u & 0x80000000u) ? (u & 0x7FFFFFFFu) : ~u;
    return __uint_as_float(b);
}
__device__ __forceinline__ unsigned short bf16rne(float f) {
    u32 u = __float_as_uint(f);
    u32 r = (u + 0x7FFFu + ((u >> 16) & 1u)) >> 16;
    return (unsigned short)r;
}
__device__ __forceinline__ float bflo(u32 u) { return __uint_as_float(u << 16); }
__device__ __forceinline__ float bfhi(u32 u) { return __uint_as_float(u & 0xFFFF0000u); }
// D[15:0]=bf16(lo), D[31:16]=bf16(hi)
__device__ __forceinline__ u32 cvtpk(float lo, float hi) {
    u32 r;
    asm("v_cvt_pk_bf16_f32 %0, %1, %2" : "=v"(r) : "v"(lo), "v"(hi));
    return r;
}

// ---------- K_pq_hist: heterogeneous grid ----------
// [0, npc):      per-chunk bucket histogram g1[s*npc + c]
// [npc, ...):    per-node tables Pb/Qb (bf16-packed), LDS-transposed coalesced writes
__global__ __launch_bounds__(256) void k_pq_hist(
    const float* __restrict__ x, const float* __restrict__ W1, const float* __restrict__ b1,
    const int* __restrict__ ei,
    u32* __restrict__ Pb, u32* __restrict__ Qb, u32* __restrict__ g1,
    int N, int E, int NSB, int npc)
{
    __shared__ u32 smem[4224];     // 16.5 KB, aliased by both roles
    int tid = threadIdx.x;
    int bid = (int)blockIdx.x;

    if (bid < npc) {
        // ---- per-chunk bucket histogram ----
        u32* cnt = smem;           // [NSB] (NSB <= 512 guaranteed by host)
        int c = bid;
        for (int s = tid; s < NSB; s += 256) cnt[s] = 0;
        __syncthreads();
        int s0 = c * CHP, end = min(E, s0 + CHP);
        int nq = (end - s0) >> 2;  // host guarantees E%4==0
        const int4* d4p = (const int4*)(ei + (size_t)E + s0);
        for (int qi = tid; qi < nq; qi += 256) {
            int4 d4 = d4p[qi];
            atomicAdd(&cnt[d4.x >> NPB_SHIFT], 1u);
            atomicAdd(&cnt[d4.y >> NPB_SHIFT], 1u);
            atomicAdd(&cnt[d4.z >> NPB_SHIFT], 1u);
            atomicAdd(&cnt[d4.w >> NPB_SHIFT], 1u);
        }
        __syncthreads();
        for (int s = tid; s < NSB; s += 256) g1[(size_t)s * npc + c] = cnt[s];
        return;
    }

    // ---- PQ role ----
    float* sWTa = (float*)smem;            // [j][k] = W1[k][j]-W1[k+32][j]
    float* sWTb = (float*)smem + 2048;     // [j][k] = W1[k+32][j]
    for (int idx = tid; idx < 2048; idx += 256) {
        int j = idx >> 5, k = idx & 31;
        float a = W1[k * 64 + j];
        float b = W1[(k + 32) * 64 + j];
        sWTa[j * 32 + k] = a - b;
        sWTb[j * 32 + k] = b;
    }
    __syncthreads();

    int blk = bid - npc;
    int n = blk * 256 + tid;

    u32 pw[32], qw[32];
    if (n < N) {
        float xr[32];
        const float4* x4 = reinterpret_cast<const float4*>(x + (size_t)n * 32);
#pragma unroll
        for (int q = 0; q < 8; ++q) {
            float4 v = x4[q];
            xr[4 * q] = v.x; xr[4 * q + 1] = v.y; xr[4 * q + 2] = v.z; xr[4 * q + 3] = v.w;
        }
        for (int j0 = 0; j0 < 64; j0 += 4) {
            float pv[4], qv[4];
#pragma unroll
            for (int m = 0; m < 4; ++m) {
                int j = j0 + m;
                float a = b1[j], q = 0.f;
#pragma unroll
                for (int k = 0; k < 32; ++k) {
                    a = fmaf(xr[k], sWTa[j * 32 + k], a);
                    q = fmaf(xr[k], sWTb[j * 32 + k], q);
                }
                pv[m] = a; qv[m] = q;
            }
            pw[(j0 >> 1)]     = (u32)bf16rne(pv[0]) | ((u32)bf16rne(pv[1]) << 16);
            pw[(j0 >> 1) + 1] = (u32)bf16rne(pv[2]) | ((u32)bf16rne(pv[3]) << 16);
            qw[(j0 >> 1)]     = (u32)bf16rne(qv[0]) | ((u32)bf16rne(qv[1]) << 16);
            qw[(j0 >> 1) + 1] = (u32)bf16rne(qv[2]) | ((u32)bf16rne(qv[3]) << 16);
        }
    }
    __syncthreads();   // weights dead; smem re-used as staging

    u32* sP = smem;            // [64][33] padded
    u32* sQ = smem + 2112;
    for (int r = 0; r < 4; ++r) {
        if ((tid >> 6) == r && n < N) {
            int row = tid & 63;
#pragma unroll
            for (int i = 0; i < 32; ++i) {
                sP[row * 33 + i] = pw[i];
                sQ[row * 33 + i] = qw[i];
            }
        }
        __syncthreads();
        int nodebase = blk * 256 + r * 64;
        size_t wbase = (size_t)nodebase * 32;
        for (int w = tid; w < 2048; w += 256) {
            int node = nodebase + (w >> 5);
            if (node < N) {
                u32 v = sP[(w >> 5) * 33 + (w & 31)];
                u32 u = sQ[(w >> 5) * 33 + (w & 31)];
                Pb[wbase + w] = v;
                Qb[wbase + w] = u;
            }
        }
        __syncthreads();
    }
}

// ---------- generic partial scan (1024/block) + block-sum scan, for g1 ----------
__global__ __launch_bounds__(256) void k_scan1(const u32* __restrict__ deg, u32* __restrict__ cursor,
                                               u32* __restrict__ bsum, int N) {
    __shared__ u32 sh[256];
    int t = threadIdx.x;
    int base = blockIdx.x * 1024 + t * 4;
    u32 v0 = 0, v1 = 0, v2 = 0, v3 = 0;
    if (base + 3 < N) {
        uint4 vv = *reinterpret_cast<const uint4*>(deg + base);
        v0 = vv.x; v1 = vv.y; v2 = vv.z; v3 = vv.w;
    } else {
        if (base < N) v0 = deg[base];
        if (base + 1 < N) v1 = deg[base + 1];
        if (base + 2 < N) v2 = deg[base + 2];
        if (base + 3 < N) v3 = deg[base + 3];
    }
    u32 s = v0 + v1 + v2 + v3;
    sh[t] = s; __syncthreads();
    u32 acc = s;
    for (int off = 1; off < 256; off <<= 1) {
        u32 add = (t >= off) ? sh[t - off] : 0;
        __syncthreads();
        acc += add; sh[t] = acc;
        __syncthreads();
    }
    u32 excl = acc - s;
    if (base < N) cursor[base] = excl;
    if (base + 1 < N) cursor[base + 1] = excl + v0;
    if (base + 2 < N) cursor[base + 2] = excl + v0 + v1;
    if (base + 3 < N) cursor[base + 3] = excl + v0 + v1 + v2;
    if (t == 255) bsum[blockIdx.x] = acc;
}

__global__ __launch_bounds__(256) void k_scan2(const u32* __restrict__ bsum, u32* __restrict__ bsumX, int nb) {
    __shared__ u32 sh[256];
    int t = threadIdx.x;
    u32 v = (t < nb) ? bsum[t] : 0;
    sh[t] = v; __syncthreads();
    u32 acc = v;
    for (int off = 1; off < 256; off <<= 1) {
        u32 add = (t >= off) ? sh[t - off] : 0;
        __syncthreads();
        acc += add; sh[t] = acc;
        __syncthreads();
    }
    if (t < nb) bsumX[t] = acc - v;
}

// ---------- K_sp1: scatter u32 records into coarse buckets (deterministic bases) ----------
// record: src (17b) | local (8b) << 17
__global__ __launch_bounds__(512) void k_sp1(const int* __restrict__ ei,
                                             const u32* __restrict__ g1cur, const u32* __restrict__ bsumX1,
                                             u32* __restrict__ sorted, int E, int NSB, int npc) {
    __shared__ u32 sb[512], cnt[512];
    int tid = threadIdx.x;
    int c = (int)blockIdx.x;
    for (int s = tid; s < NSB; s += 512) {
        size_t idx = (size_t)s * npc + c;
        sb[s] = g1cur[idx] + bsumX1[idx >> 10];
        cnt[s] = 0;
    }
    __syncthreads();
    int s0 = c * CHP, end = min(E, s0 + CHP);
    int nq = (end - s0) >> 2;
    const int4* d4p = (const int4*)(ei + (size_t)E + s0);
    const int4* s4p = (const int4*)(ei + s0);
    for (int qi = tid; qi < nq; qi += 512) {
        int4 d4 = d4p[qi];
        int4 s4 = s4p[qi];
        int dd[4] = {d4.x, d4.y, d4.z, d4.w};
        int ss[4] = {s4.x, s4.y, s4.z, s4.w};
#pragma unroll
        for (int u = 0; u < 4; ++u) {
            int s = dd[u] >> NPB_SHIFT;
            u32 r = atomicAdd(&cnt[s], 1u);
            sorted[sb[s] + r] = (u32)ss[u] | ((u32)(dd[u] & (NPB - 1)) << 17);
        }
    }
}

// ---------- K_bucket: 2 blocks x 512 threads (8 waves) per bucket; pipelined gather + MFMA ----------
// + LDS max-agg; flush = coalesced encoded atomicMax into eout (order-independent, deterministic)
// A-frag (16x16x32 bf16): lane l holds A[row=l&15][k=(l>>4)*8 + j]
// C/D (m89-verified):     lane l, reg i -> D[row=(l>>4)*4+i][col=l&15]
__global__ __launch_bounds__(512) void k_bucket(
    const u32* __restrict__ Pb, const u32* __restrict__ Qb,
    const u32* __restrict__ sorted, const u32* __restrict__ g1cur, const u32* __restrict__ bsumX1,
    const float* __restrict__ W2,
    u32* __restrict__ eout, int E, int N, int NSB, int npc)
{
    __shared__ u32 agg[NPB * 32];   // 32 KB, encoded-u32 max, 0 = "untouched"
    int b    = (int)blockIdx.x >> 1;
    int half = (int)blockIdx.x & 1;
    int tid = threadIdx.x;
    for (int i = tid; i < NPB * 32; i += 512) agg[i] = 0u;

    int lane = tid & 63;
    int wid = tid >> 6;            // 0..7
    int n = lane & 15;
    int kc = lane >> 4;

    // W2 resident as 4 bf16 B-fragments
    short8v b00, b01, b10, b11;
#pragma unroll
    for (int j = 0; j < 8; ++j) {
        int k = kc * 8 + j;
        b00[j] = (short)bf16rne(W2[k * 32 + n]);
        b01[j] = (short)bf16rne(W2[(k + 32) * 32 + n]);
        b10[j] = (short)bf16rne(W2[k * 32 + n + 16]);
        b11[j] = (short)bf16rne(W2[(k + 32) * 32 + n + 16]);
    }

    size_t i0 = (size_t)b * npc;
    u32 start = g1cur[i0] + bsumX1[i0 >> 10];
    u32 bend;
    if (b + 1 < NSB) {
        size_t i1 = (size_t)(b + 1) * npc;
        bend = g1cur[i1] + bsumX1[i1 >> 10];
    } else {
        bend = (u32)E;
    }
    int ntiles = ((int)(bend - start) + 15) >> 4;
    int nt0 = (ntiles + 1) >> 1;            // half 0 takes tiles [0, nt0), half 1 [nt0, ntiles)
    int tb = half ? nt0 : 0;
    int te = half ? ntiles : nt0;
    int nodebase = b << NPB_SHIFT;

    __syncthreads();

    int t = tb + wid;
    u32 slotA = start + (u32)t * 16u + (u32)n;
    u32 recA = 0;
    uint4 qA0, qA1, pA0, pA1;
    if (t < te) {   // wave-uniform branch
        u32 sl = slotA < bend ? slotA : bend - 1;
        recA = sorted[sl];
        int src = (int)(recA & 0x1FFFFu);
        int loc = (int)(recA >> 17);
        const u32* qr = Qb + (size_t)src * 32;
        const u32* pr = Pb + (size_t)(nodebase + loc) * 32;
        qA0 = *(const uint4*)(qr + kc * 4);
        qA1 = *(const uint4*)(qr + 16 + kc * 4);
        pA0 = *(const uint4*)(pr + kc * 4);
        pA1 = *(const uint4*)(pr + 16 + kc * 4);
    }

    for (; t < te; t += 8) {
        // ---- prefetch next tile for this wave (clamped-safe) ----
        u32 slotB = start + (u32)(t + 8) * 16u + (u32)n;
        u32 slB = slotB < bend ? slotB : bend - 1;
        u32 recB = sorted[slB];
        int srcB = (int)(recB & 0x1FFFFu);
        int locB = (int)(recB >> 17);
        const u32* qrB = Qb + (size_t)srcB * 32;
        const u32* prB = Pb + (size_t)(nodebase + locB) * 32;
        uint4 qB0 = *(const uint4*)(qrB + kc * 4);
        uint4 qB1 = *(const uint4*)(qrB + 16 + kc * 4);
        uint4 pB0 = *(const uint4*)(prB + kc * 4);
        uint4 pB1 = *(const uint4*)(prB + 16 + kc * 4);

        // ---- compute current tile ----
        bool valid = slotA < bend;
        int local = valid ? (int)(recA >> 17) : -1;

        u32 pa[4] = {pA0.x, pA0.y, pA0.z, pA0.w};
        u32 ph[4] = {pA1.x, pA1.y, pA1.z, pA1.w};
        u32 qa[4] = {qA0.x, qA0.y, qA0.z, qA0.w};
        u32 qh[4] = {qA1.x, qA1.y, qA1.z, qA1.w};

        u32x4 aw0, aw1;
#pragma unroll
        for (int u = 0; u < 4; ++u) {
            float l0 = fmaxf(bflo(pa[u]) + bflo(qa[u]), 0.f);
            float h0 = fmaxf(bfhi(pa[u]) + bfhi(qa[u]), 0.f);
            aw0[u] = cvtpk(l0, h0);
            float l1 = fmaxf(bflo(ph[u]) + bflo(qh[u]), 0.f);
            float h1 = fmaxf(bfhi(ph[u]) + bfhi(qh[u]), 0.f);
            aw1[u] = cvtpk(l1, h1);
        }
        short8v a0 = __builtin_bit_cast(short8v, aw0);
        short8v a1 = __builtin_bit_cast(short8v, aw1);

        f32x4 d0 = {0.f, 0.f, 0.f, 0.f};
        f32x4 d1 = {0.f, 0.f, 0.f, 0.f};
        d0 = __builtin_amdgcn_mfma_f32_16x16x32_bf16(a0, b00, d0, 0, 0, 0);
        d0 = __builtin_amdgcn_mfma_f32_16x16x32_bf16(a1, b01, d0, 0, 0, 0);
        d1 = __builtin_amdgcn_mfma_f32_16x16x32_bf16(a0, b10, d1, 0, 0, 0);
        d1 = __builtin_amdgcn_mfma_f32_16x16x32_bf16(a1, b11, d1, 0, 0, 0);

        // rows owned by this lane: r = kc*4 + i; row r's record lives in lane r
#pragma unroll
        for (int i = 0; i < 4; ++i) {
            int r = kc * 4 + i;
            int lr = __shfl(local, r, 64);
            if (lr >= 0) {
                int sw = (lr & 1) << 4;
                atomicMax(&agg[(lr << 5) + (n ^ sw)], enc_f32(d0[i]));
                atomicMax(&agg[(lr << 5) + ((n + 16) ^ sw)], enc_f32(d1[i]));
            }
        }

        // ---- rotate ----
        slotA = slotB; recA = recB;
        qA0 = qB0; qA1 = qB1; pA0 = pB0; pA1 = pB1;
    }

    __syncthreads();
    // coalesced merge into global encoded buffer (atomicMax is order-independent -> deterministic)
    for (int i = tid; i < NPB * 32; i += 512) {
        int local = i >> 5, c = i & 31;
        int node = nodebase + local;
        if (node < N) {
            u32 v = agg[(local << 5) + (c ^ ((local & 1) << 4))];
            if (v) atomicMax(&eout[(size_t)node * 32 + c], v);
        }
    }
}

// ---------- K_decode: in-place decode + b2; sentinel 0 -> 0.0 (no incoming edges) ----------
__global__ __launch_bounds__(256) void k_decode(u32* __restrict__ buf, const float* __restrict__ b2, int n) {
    int i = blockIdx.x * 256 + threadIdx.x;
    if (i >= n) return;
    u32 u = buf[i];
    float f = u ? (dec_f32(u) + b2[i & 31]) : 0.f;
    reinterpret_cast<float*>(buf)[i] = f;
}

// ---------- fallback (round-1 style) ----------
__global__ __launch_bounds__(256) void fb_edge(const float* __restrict__ x, const int* __restrict__ ei,
                                               const float* __restrict__ W1, const float* __restrict__ b1,
                                               const float* __restrict__ W2, const float* __restrict__ b2,
                                               u32* __restrict__ out, int E) {
    int e = blockIdx.x * 256 + threadIdx.x;
    if (e >= E) return;
    int src = ei[e], dst = ei[E + e];
    float m[64];
    const float4* xi4 = reinterpret_cast<const float4*>(x + (size_t)dst * 32);
    const float4* xj4 = reinterpret_cast<const float4*>(x + (size_t)src * 32);
#pragma unroll
    for (int q = 0; q < 8; ++q) {
        float4 a = xi4[q], b = xj4[q];
        m[q * 4] = a.x; m[q * 4 + 1] = a.y; m[q * 4 + 2] = a.z; m[q * 4 + 3] = a.w;
        m[32 + q * 4] = b.x - a.x; m[32 + q * 4 + 1] = b.y - a.y;
        m[32 + q * 4 + 2] = b.z - a.z; m[32 + q * 4 + 3] = b.w - a.w;
    }
    float acc[32];
#pragma unroll
    for (int c = 0; c < 32; ++c) acc[c] = b2[c];
    for (int j = 0; j < 64; ++j) {
        float h = b1[j];
#pragma unroll
        for (int k = 0; k < 64; ++k) h = fmaf(m[k], W1[k * 64 + j], h);
        h = fmaxf(h, 0.0f);
#pragma unroll
        for (int c = 0; c < 32; ++c) acc[c] = fmaf(h, W2[j * 32 + c], acc[c]);
    }
    u32* o = out + (size_t)dst * 32;
#pragma unroll
    for (int c = 0; c < 32; ++c) atomicMax(o + c, enc_f32(acc[c]));
}
__global__ __launch_bounds__(256) void fb_decode(u32* __restrict__ buf, int n) {
    int i = blockIdx.x * 256 + threadIdx.x;
    if (i >= n) return;
    u32 u = buf[i];
    reinterpret_cast<float*>(buf)[i] = u ? dec_f32(u) : 0.f;
}

extern "C" void kernel_launch(void* const* d_in, const int* in_sizes, int n_in,
                              void* d_out, int out_size, void* d_ws, size_t ws_size,
                              hipStream_t stream) {
    const float* x  = (const float*)d_in[0];
    const int*   ei = (const int*)d_in[1];
    const float* W1 = (const float*)d_in[2];
    const float* b1 = (const float*)d_in[3];
    const float* W2 = (const float*)d_in[4];
    const float* b2 = (const float*)d_in[5];

    int N = in_sizes[0] / 32;
    int E = in_sizes[1] / 2;
    int NSB = (N + NPB - 1) >> NPB_SHIFT;       // 391 buckets of 256 nodes
    int npc = (E + CHP - 1) / CHP;              // 391 chunks
    int M1  = NSB * npc;                        // flat hist (152881)
    int nb1 = (M1 + 1023) / 1024;

    // workspace layout (256B aligned)
    char* ws = (char*)d_ws;
    size_t off = 0;
    auto alloc = [&](size_t bytes) { char* p = ws + off; off += (bytes + 255) & ~(size_t)255; return p; };
    u32*   Pb     = (u32*)alloc((size_t)N * 32 * 4);
    u32*   Qb     = (u32*)alloc((size_t)N * 32 * 4);
    u32*   g1     = (u32*)alloc((size_t)M1 * 4);
    u32*   g1cur  = (u32*)alloc((size_t)M1 * 4);
    u32*   bsum1  = (u32*)alloc(256 * 4);
    u32*   bsumX1 = (u32*)alloc(256 * 4);
    u32*   sorted = (u32*)alloc((size_t)E * 4);
    // NSB<=512 (sp1 LDS arrays), src fits 17b, E%4 for quad streams, M1 scan fits
    bool fits = (off <= ws_size) && (NSB <= 512) && (N < (1 << 17)) &&
                ((E & 3) == 0) && (nb1 <= 256);

    if (!fits) {
        hipMemsetAsync(d_out, 0, (size_t)out_size * 4, stream);
        int be = (E + 255) / 256;
        fb_edge<<<be, 256, 0, stream>>>(x, ei, W1, b1, W2, b2, (u32*)d_out, E);
        fb_decode<<<(out_size + 255) / 256, 256, 0, stream>>>((u32*)d_out, out_size);
        return;
    }

    hipMemsetAsync(d_out, 0, (size_t)out_size * 4, stream);   // encoded-max sentinel

    int pq_blocks = (N + 255) / 256;
    k_pq_hist<<<npc + pq_blocks, 256, 0, stream>>>(x, W1, b1, ei, Pb, Qb, g1, N, E, NSB, npc);

    k_scan1<<<nb1, 256, 0, stream>>>(g1, g1cur, bsum1, M1);
    k_scan2<<<1, 256, 0, stream>>>(bsum1, bsumX1, nb1);

    k_sp1<<<npc, 512, 0, stream>>>(ei, g1cur, bsumX1, sorted, E, NSB, npc);

    k_bucket<<<2 * NSB, 512, 0, stream>>>(Pb, Qb, sorted, g1cur, bsumX1, W2,
                                          (u32*)d_out, E, N, NSB, npc);

    k_decode<<<(out_size + 255) / 256, 256, 0, stream>>>((u32*)d_out, b2, out_size);
}

// Round 12
// 143.075 us; speedup vs baseline: 1.0963x; 1.0963x over previous
//
#include <hip/hip_runtime.h>

typedef unsigned int u32;
typedef __attribute__((ext_vector_type(8))) short short8v;
typedef __attribute__((ext_vector_type(4))) u32 u32x4;
typedef __attribute__((ext_vector_type(4))) float f32x4;

#define NPB 128          // nodes per bucket (sort + aggregation granularity)
#define NPB_SHIFT 7
#define CHP 4096         // edges per chunk (hist + scatter)

// order-preserving float<->uint encoding; enc never returns 0 for real values
__device__ __forceinline__ u32 enc_f32(float f) {
    u32 b = __float_as_uint(f);
    return (b & 0x80000000u) ? ~b : (b | 0x80000000u);
}
__device__ __forceinline__ float dec_f32(u32 u) {
    u32 b = (u & 0x80000000u) ? (u & 0x7FFFFFFFu) : ~u;
    return __uint_as_float(b);
}
__device__ __forceinline__ unsigned short bf16rne(float f) {
    u32 u = __float_as_uint(f);
    u32 r = (u + 0x7FFFu + ((u >> 16) & 1u)) >> 16;
    return (unsigned short)r;
}
__device__ __forceinline__ float bflo(u32 u) { return __uint_as_float(u << 16); }
__device__ __forceinline__ float bfhi(u32 u) { return __uint_as_float(u & 0xFFFF0000u); }
// D[15:0]=bf16(lo), D[31:16]=bf16(hi)
__device__ __forceinline__ u32 cvtpk(float lo, float hi) {
    u32 r;
    asm("v_cvt_pk_bf16_f32 %0, %1, %2" : "=v"(r) : "v"(lo), "v"(hi));
    return r;
}

// ---------- K_pq_hist: heterogeneous grid ----------
// [0, npc):      per-chunk bucket histogram g1[s*npc + c]
// [npc, ...):    per-node tables Pb/Qb (bf16-packed), LDS-transposed coalesced writes
__global__ __launch_bounds__(256) void k_pq_hist(
    const float* __restrict__ x, const float* __restrict__ W1, const float* __restrict__ b1,
    const int* __restrict__ ei,
    u32* __restrict__ Pb, u32* __restrict__ Qb, u32* __restrict__ g1,
    int N, int E, int NSB, int npc)
{
    __shared__ u32 smem[4224];     // 16.5 KB, aliased by both roles
    int tid = threadIdx.x;
    int bid = (int)blockIdx.x;

    if (bid < npc) {
        // ---- per-chunk bucket histogram ----
        u32* cnt = smem;           // [NSB] (NSB <= 1024 guaranteed by host)
        int c = bid;
        for (int s = tid; s < NSB; s += 256) cnt[s] = 0;
        __syncthreads();
        int s0 = c * CHP, end = min(E, s0 + CHP);
        int nq = (end - s0) >> 2;  // host guarantees E%4==0
        const int4* d4p = (const int4*)(ei + (size_t)E + s0);
        for (int qi = tid; qi < nq; qi += 256) {
            int4 d4 = d4p[qi];
            atomicAdd(&cnt[d4.x >> NPB_SHIFT], 1u);
            atomicAdd(&cnt[d4.y >> NPB_SHIFT], 1u);
            atomicAdd(&cnt[d4.z >> NPB_SHIFT], 1u);
            atomicAdd(&cnt[d4.w >> NPB_SHIFT], 1u);
        }
        __syncthreads();
        for (int s = tid; s < NSB; s += 256) g1[(size_t)s * npc + c] = cnt[s];
        return;
    }

    // ---- PQ role ----
    float* sWTa = (float*)smem;            // [j][k] = W1[k][j]-W1[k+32][j]
    float* sWTb = (float*)smem + 2048;     // [j][k] = W1[k+32][j]
    for (int idx = tid; idx < 2048; idx += 256) {
        int j = idx >> 5, k = idx & 31;
        float a = W1[k * 64 + j];
        float b = W1[(k + 32) * 64 + j];
        sWTa[j * 32 + k] = a - b;
        sWTb[j * 32 + k] = b;
    }
    __syncthreads();

    int blk = bid - npc;
    int n = blk * 256 + tid;

    u32 pw[32], qw[32];
    if (n < N) {
        float xr[32];
        const float4* x4 = reinterpret_cast<const float4*>(x + (size_t)n * 32);
#pragma unroll
        for (int q = 0; q < 8; ++q) {
            float4 v = x4[q];
            xr[4 * q] = v.x; xr[4 * q + 1] = v.y; xr[4 * q + 2] = v.z; xr[4 * q + 3] = v.w;
        }
        for (int j0 = 0; j0 < 64; j0 += 4) {
            float pv[4], qv[4];
#pragma unroll
            for (int m = 0; m < 4; ++m) {
                int j = j0 + m;
                float a = b1[j], q = 0.f;
#pragma unroll
                for (int k = 0; k < 32; ++k) {
                    a = fmaf(xr[k], sWTa[j * 32 + k], a);
                    q = fmaf(xr[k], sWTb[j * 32 + k], q);
                }
                pv[m] = a; qv[m] = q;
            }
            pw[(j0 >> 1)]     = (u32)bf16rne(pv[0]) | ((u32)bf16rne(pv[1]) << 16);
            pw[(j0 >> 1) + 1] = (u32)bf16rne(pv[2]) | ((u32)bf16rne(pv[3]) << 16);
            qw[(j0 >> 1)]     = (u32)bf16rne(qv[0]) | ((u32)bf16rne(qv[1]) << 16);
            qw[(j0 >> 1) + 1] = (u32)bf16rne(qv[2]) | ((u32)bf16rne(qv[3]) << 16);
        }
    }
    __syncthreads();   // weights dead; smem re-used as staging

    u32* sP = smem;            // [64][33] padded
    u32* sQ = smem + 2112;
    for (int r = 0; r < 4; ++r) {
        if ((tid >> 6) == r && n < N) {
            int row = tid & 63;
#pragma unroll
            for (int i = 0; i < 32; ++i) {
                sP[row * 33 + i] = pw[i];
                sQ[row * 33 + i] = qw[i];
            }
        }
        __syncthreads();
        int nodebase = blk * 256 + r * 64;
        size_t wbase = (size_t)nodebase * 32;
        for (int w = tid; w < 2048; w += 256) {
            int node = nodebase + (w >> 5);
            if (node < N) {
                u32 v = sP[(w >> 5) * 33 + (w & 31)];
                u32 u = sQ[(w >> 5) * 33 + (w & 31)];
                Pb[wbase + w] = v;
                Qb[wbase + w] = u;
            }
        }
        __syncthreads();
    }
}

// ---------- partial scan, 2048 items/block (8/thread) + block-sum scan ----------
__global__ __launch_bounds__(256) void k_scan1(const u32* __restrict__ deg, u32* __restrict__ cursor,
                                               u32* __restrict__ bsum, int M) {
    __shared__ u32 sh[256];
    int t = threadIdx.x;
    int base = blockIdx.x * 2048 + t * 8;
    u32 v[8];
    if (base + 7 < M) {
        uint4 a = *reinterpret_cast<const uint4*>(deg + base);
        uint4 b = *reinterpret_cast<const uint4*>(deg + base + 4);
        v[0] = a.x; v[1] = a.y; v[2] = a.z; v[3] = a.w;
        v[4] = b.x; v[5] = b.y; v[6] = b.z; v[7] = b.w;
    } else {
#pragma unroll
        for (int i = 0; i < 8; ++i) v[i] = (base + i < M) ? deg[base + i] : 0;
    }
    u32 s = 0;
#pragma unroll
    for (int i = 0; i < 8; ++i) s += v[i];
    sh[t] = s; __syncthreads();
    u32 acc = s;
    for (int off = 1; off < 256; off <<= 1) {
        u32 add = (t >= off) ? sh[t - off] : 0;
        __syncthreads();
        acc += add; sh[t] = acc;
        __syncthreads();
    }
    u32 run = acc - s;
#pragma unroll
    for (int i = 0; i < 8; ++i) {
        if (base + i < M) cursor[base + i] = run;
        run += v[i];
    }
    if (t == 255) bsum[blockIdx.x] = acc;
}

__global__ __launch_bounds__(256) void k_scan2(const u32* __restrict__ bsum, u32* __restrict__ bsumX, int nb) {
    __shared__ u32 sh[256];
    int t = threadIdx.x;
    u32 v = (t < nb) ? bsum[t] : 0;
    sh[t] = v; __syncthreads();
    u32 acc = v;
    for (int off = 1; off < 256; off <<= 1) {
        u32 add = (t >= off) ? sh[t - off] : 0;
        __syncthreads();
        acc += add; sh[t] = acc;
        __syncthreads();
    }
    if (t < nb) bsumX[t] = acc - v;
}

// ---------- K_sp1: scatter u32 records into buckets (deterministic bases) ----------
// record: src (17b) | local (7b) << 17
__global__ __launch_bounds__(512) void k_sp1(const int* __restrict__ ei,
                                             const u32* __restrict__ g1cur, const u32* __restrict__ bsumX1,
                                             u32* __restrict__ sorted, int E, int NSB, int npc) {
    __shared__ u32 sb[1024], cnt[1024];
    int tid = threadIdx.x;
    int c = (int)blockIdx.x;
    for (int s = tid; s < NSB; s += 512) {
        size_t idx = (size_t)s * npc + c;
        sb[s] = g1cur[idx] + bsumX1[idx >> 11];
        cnt[s] = 0;
    }
    __syncthreads();
    int s0 = c * CHP, end = min(E, s0 + CHP);
    int nq = (end - s0) >> 2;
    const int4* d4p = (const int4*)(ei + (size_t)E + s0);
    const int4* s4p = (const int4*)(ei + s0);
    for (int qi = tid; qi < nq; qi += 512) {
        int4 d4 = d4p[qi];
        int4 s4 = s4p[qi];
        int dd[4] = {d4.x, d4.y, d4.z, d4.w};
        int ss[4] = {s4.x, s4.y, s4.z, s4.w};
#pragma unroll
        for (int u = 0; u < 4; ++u) {
            int s = dd[u] >> NPB_SHIFT;
            u32 r = atomicAdd(&cnt[s], 1u);
            sorted[sb[s] + r] = (u32)ss[u] | ((u32)(dd[u] & (NPB - 1)) << 17);
        }
    }
}

// ---------- K_bucket: one 512-thread block (8 waves) per 128-node bucket ----------
// pipelined gather + MFMA + LDS max-agg; direct final store (exclusive ownership)
// A-frag (16x16x32 bf16): lane l holds A[row=l&15][k=(l>>4)*8 + j]
// C/D (m89-verified):     lane l, reg i -> D[row=(l>>4)*4+i][col=l&15]
__global__ __launch_bounds__(512) void k_bucket(
    const u32* __restrict__ Pb, const u32* __restrict__ Qb,
    const u32* __restrict__ sorted, const u32* __restrict__ g1cur, const u32* __restrict__ bsumX1,
    const float* __restrict__ W2, const float* __restrict__ b2,
    float* __restrict__ out, int E, int N, int NSB, int npc)
{
    __shared__ u32 agg[NPB * 32];   // 16 KB, encoded-u32 max, 0 = "untouched"
    int b = (int)blockIdx.x;
    int tid = threadIdx.x;
    for (int i = tid; i < NPB * 32; i += 512) agg[i] = 0u;

    int lane = tid & 63;
    int wid = tid >> 6;            // 0..7
    int n = lane & 15;
    int kc = lane >> 4;

    // W2 resident as 4 bf16 B-fragments
    short8v b00, b01, b10, b11;
#pragma unroll
    for (int j = 0; j < 8; ++j) {
        int k = kc * 8 + j;
        b00[j] = (short)bf16rne(W2[k * 32 + n]);
        b01[j] = (short)bf16rne(W2[(k + 32) * 32 + n]);
        b10[j] = (short)bf16rne(W2[k * 32 + n + 16]);
        b11[j] = (short)bf16rne(W2[(k + 32) * 32 + n + 16]);
    }

    size_t i0 = (size_t)b * npc;
    u32 start = g1cur[i0] + bsumX1[i0 >> 11];
    u32 bend;
    if (b + 1 < NSB) {
        size_t i1 = (size_t)(b + 1) * npc;
        bend = g1cur[i1] + bsumX1[i1 >> 11];
    } else {
        bend = (u32)E;
    }
    int ntiles = ((int)(bend - start) + 15) >> 4;
    int nodebase = b << NPB_SHIFT;

    __syncthreads();

    int t = wid;
    u32 slotA = start + (u32)t * 16u + (u32)n;
    u32 recA = 0;
    uint4 qA0, qA1, pA0, pA1;
    if (t < ntiles) {   // wave-uniform branch
        u32 sl = slotA < bend ? slotA : bend - 1;
        recA = sorted[sl];
        int src = (int)(recA & 0x1FFFFu);
        int loc = (int)(recA >> 17);
        const u32* qr = Qb + (size_t)src * 32;
        const u32* pr = Pb + (size_t)(nodebase + loc) * 32;
        qA0 = *(const uint4*)(qr + kc * 4);
        qA1 = *(const uint4*)(qr + 16 + kc * 4);
        pA0 = *(const uint4*)(pr + kc * 4);
        pA1 = *(const uint4*)(pr + 16 + kc * 4);
    }

    for (; t < ntiles; t += 8) {
        // ---- prefetch next tile for this wave (clamped-safe) ----
        u32 slotB = start + (u32)(t + 8) * 16u + (u32)n;
        u32 slB = slotB < bend ? slotB : bend - 1;
        u32 recB = sorted[slB];
        int srcB = (int)(recB & 0x1FFFFu);
        int locB = (int)(recB >> 17);
        const u32* qrB = Qb + (size_t)srcB * 32;
        const u32* prB = Pb + (size_t)(nodebase + locB) * 32;
        uint4 qB0 = *(const uint4*)(qrB + kc * 4);
        uint4 qB1 = *(const uint4*)(qrB + 16 + kc * 4);
        uint4 pB0 = *(const uint4*)(prB + kc * 4);
        uint4 pB1 = *(const uint4*)(prB + 16 + kc * 4);

        // ---- compute current tile ----
        bool valid = slotA < bend;
        int local = valid ? (int)(recA >> 17) : -1;

        u32 pa[4] = {pA0.x, pA0.y, pA0.z, pA0.w};
        u32 ph[4] = {pA1.x, pA1.y, pA1.z, pA1.w};
        u32 qa[4] = {qA0.x, qA0.y, qA0.z, qA0.w};
        u32 qh[4] = {qA1.x, qA1.y, qA1.z, qA1.w};

        u32x4 aw0, aw1;
#pragma unroll
        for (int u = 0; u < 4; ++u) {
            float l0 = fmaxf(bflo(pa[u]) + bflo(qa[u]), 0.f);
            float h0 = fmaxf(bfhi(pa[u]) + bfhi(qa[u]), 0.f);
            aw0[u] = cvtpk(l0, h0);
            float l1 = fmaxf(bflo(ph[u]) + bflo(qh[u]), 0.f);
            float h1 = fmaxf(bfhi(ph[u]) + bfhi(qh[u]), 0.f);
            aw1[u] = cvtpk(l1, h1);
        }
        short8v a0 = __builtin_bit_cast(short8v, aw0);
        short8v a1 = __builtin_bit_cast(short8v, aw1);

        f32x4 d0 = {0.f, 0.f, 0.f, 0.f};
        f32x4 d1 = {0.f, 0.f, 0.f, 0.f};
        d0 = __builtin_amdgcn_mfma_f32_16x16x32_bf16(a0, b00, d0, 0, 0, 0);
        d0 = __builtin_amdgcn_mfma_f32_16x16x32_bf16(a1, b01, d0, 0, 0, 0);
        d1 = __builtin_amdgcn_mfma_f32_16x16x32_bf16(a0, b10, d1, 0, 0, 0);
        d1 = __builtin_amdgcn_mfma_f32_16x16x32_bf16(a1, b11, d1, 0, 0, 0);

        // rows owned by this lane: r = kc*4 + i; row r's record lives in lane r
#pragma unroll
        for (int i = 0; i < 4; ++i) {
            int r = kc * 4 + i;
            int lr = __shfl(local, r, 64);
            if (lr >= 0) {
                int sw = (lr & 1) << 4;
                atomicMax(&agg[(lr << 5) + (n ^ sw)], enc_f32(d0[i]));
                atomicMax(&agg[(lr << 5) + ((n + 16) ^ sw)], enc_f32(d1[i]));
            }
        }

        // ---- rotate ----
        slotA = slotB; recA = recB;
        qA0 = qB0; qA1 = qB1; pA0 = pB0; pA1 = pB1;
    }

    __syncthreads();
    // fused decode + b2 + empty->0; exclusive bucket ownership -> plain coalesced store
    for (int i = tid; i < NPB * 32; i += 512) {
        int local = i >> 5, c = i & 31;
        int node = nodebase + local;
        if (node < N) {
            u32 u = agg[(local << 5) + (c ^ ((local & 1) << 4))];
            out[(size_t)node * 32 + c] = u ? (dec_f32(u) + b2[c]) : 0.f;
        }
    }
}

// ---------- fallback (round-1 style) ----------
__global__ __launch_bounds__(256) void fb_edge(const float* __restrict__ x, const int* __restrict__ ei,
                                               const float* __restrict__ W1, const float* __restrict__ b1,
                                               const float* __restrict__ W2, const float* __restrict__ b2,
                                               u32* __restrict__ out, int E) {
    int e = blockIdx.x * 256 + threadIdx.x;
    if (e >= E) return;
    int src = ei[e], dst = ei[E + e];
    float m[64];
    const float4* xi4 = reinterpret_cast<const float4*>(x + (size_t)dst * 32);
    const float4* xj4 = reinterpret_cast<const float4*>(x + (size_t)src * 32);
#pragma unroll
    for (int q = 0; q < 8; ++q) {
        float4 a = xi4[q], b = xj4[q];
        m[q * 4] = a.x; m[q * 4 + 1] = a.y; m[q * 4 + 2] = a.z; m[q * 4 + 3] = a.w;
        m[32 + q * 4] = b.x - a.x; m[32 + q * 4 + 1] = b.y - a.y;
        m[32 + q * 4 + 2] = b.z - a.z; m[32 + q * 4 + 3] = b.w - a.w;
    }
    float acc[32];
#pragma unroll
    for (int c = 0; c < 32; ++c) acc[c] = b2[c];
    for (int j = 0; j < 64; ++j) {
        float h = b1[j];
#pragma unroll
        for (int k = 0; k < 64; ++k) h = fmaf(m[k], W1[k * 64 + j], h);
        h = fmaxf(h, 0.0f);
#pragma unroll
        for (int c = 0; c < 32; ++c) acc[c] = fmaf(h, W2[j * 32 + c], acc[c]);
    }
    u32* o = out + (size_t)dst * 32;
#pragma unroll
    for (int c = 0; c < 32; ++c) atomicMax(o + c, enc_f32(acc[c]));
}
__global__ __launch_bounds__(256) void fb_decode(u32* __restrict__ buf, int n) {
    int i = blockIdx.x * 256 + threadIdx.x;
    if (i >= n) return;
    u32 u = buf[i];
    reinterpret_cast<float*>(buf)[i] = u ? dec_f32(u) : 0.f;
}

extern "C" void kernel_launch(void* const* d_in, const int* in_sizes, int n_in,
                              void* d_out, int out_size, void* d_ws, size_t ws_size,
                              hipStream_t stream) {
    const float* x  = (const float*)d_in[0];
    const int*   ei = (const int*)d_in[1];
    const float* W1 = (const float*)d_in[2];
    const float* b1 = (const float*)d_in[3];
    const float* W2 = (const float*)d_in[4];
    const float* b2 = (const float*)d_in[5];

    int N = in_sizes[0] / 32;
    int E = in_sizes[1] / 2;
    int NSB = (N + NPB - 1) >> NPB_SHIFT;       // 782 buckets of 128 nodes
    int npc = (E + CHP - 1) / CHP;              // 391 chunks
    int M1  = NSB * npc;                        // flat hist (305,762)
    int nb1 = (M1 + 2047) / 2048;               // 150 scan blocks

    // workspace layout (256B aligned)
    char* ws = (char*)d_ws;
    size_t off = 0;
    auto alloc = [&](size_t bytes) { char* p = ws + off; off += (bytes + 255) & ~(size_t)255; return p; };
    u32*   Pb     = (u32*)alloc((size_t)N * 32 * 4);
    u32*   Qb     = (u32*)alloc((size_t)N * 32 * 4);
    u32*   g1     = (u32*)alloc((size_t)M1 * 4);
    u32*   g1cur  = (u32*)alloc((size_t)M1 * 4);
    u32*   bsum1  = (u32*)alloc(256 * 4);
    u32*   bsumX1 = (u32*)alloc(256 * 4);
    u32*   sorted = (u32*)alloc((size_t)E * 4);
    // NSB<=1024 (sp1 LDS arrays), src fits 17b, E%4 for quad streams, M1 scan fits
    bool fits = (off <= ws_size) && (NSB <= 1024) && (N < (1 << 17)) &&
                ((E & 3) == 0) && (nb1 <= 256);

    if (!fits) {
        hipMemsetAsync(d_out, 0, (size_t)out_size * 4, stream);
        int be = (E + 255) / 256;
        fb_edge<<<be, 256, 0, stream>>>(x, ei, W1, b1, W2, b2, (u32*)d_out, E);
        fb_decode<<<(out_size + 255) / 256, 256, 0, stream>>>((u32*)d_out, out_size);
        return;
    }

    int pq_blocks = (N + 255) / 256;
    k_pq_hist<<<npc + pq_blocks, 256, 0, stream>>>(x, W1, b1, ei, Pb, Qb, g1, N, E, NSB, npc);

    k_scan1<<<nb1, 256, 0, stream>>>(g1, g1cur, bsum1, M1);
    k_scan2<<<1, 256, 0, stream>>>(bsum1, bsumX1, nb1);

    k_sp1<<<npc, 512, 0, stream>>>(ei, g1cur, bsumX1, sorted, E, NSB, npc);

    k_bucket<<<NSB, 512, 0, stream>>>(Pb, Qb, sorted, g1cur, bsumX1, W2, b2,
                                      (float*)d_out, E, N, NSB, npc);
}

// Round 13
// 141.197 us; speedup vs baseline: 1.1109x; 1.0133x over previous
//
#include <hip/hip_runtime.h>

typedef unsigned int u32;
typedef __attribute__((ext_vector_type(8))) short short8v;
typedef __attribute__((ext_vector_type(4))) u32 u32x4;
typedef __attribute__((ext_vector_type(4))) float f32x4;

#define NPB 128          // nodes per SORT bucket
#define NPB_SHIFT 7
#define SUBQ 4           // sub-buckets per sort bucket (aggregation = 32 nodes)
#define CHP 4096         // edges per chunk (hist + scatter)

// order-preserving float<->uint encoding; enc never returns 0 for real values
__device__ __forceinline__ u32 enc_f32(float f) {
    u32 b = __float_as_uint(f);
    return (b & 0x80000000u) ? ~b : (b | 0x80000000u);
}
__device__ __forceinline__ float dec_f32(u32 u) {
    u32 b = (u & 0x80000000u) ? (u & 0x7FFFFFFFu) : ~u;
    return __uint_as_float(b);
}
__device__ __forceinline__ unsigned short bf16rne(float f) {
    u32 u = __float_as_uint(f);
    u32 r = (u + 0x7FFFu + ((u >> 16) & 1u)) >> 16;
    return (unsigned short)r;
}
__device__ __forceinline__ float bflo(u32 u) { return __uint_as_float(u << 16); }
__device__ __forceinline__ float bfhi(u32 u) { return __uint_as_float(u & 0xFFFF0000u); }
// D[15:0]=bf16(lo), D[31:16]=bf16(hi)
__device__ __forceinline__ u32 cvtpk(float lo, float hi) {
    u32 r;
    asm("v_cvt_pk_bf16_f32 %0, %1, %2" : "=v"(r) : "v"(lo), "v"(hi));
    return r;
}

// ---------- K_pq_hist: heterogeneous grid ----------
// [0, npc):      per-chunk bucket histogram g1[s*npc + c]
// [npc, ...):    per-node tables Pb/Qb (bf16-packed), LDS-transposed coalesced writes
__global__ __launch_bounds__(256) void k_pq_hist(
    const float* __restrict__ x, const float* __restrict__ W1, const float* __restrict__ b1,
    const int* __restrict__ ei,
    u32* __restrict__ Pb, u32* __restrict__ Qb, u32* __restrict__ g1,
    int N, int E, int NSB, int npc)
{
    __shared__ u32 smem[4224];     // 16.5 KB, aliased by both roles
    int tid = threadIdx.x;
    int bid = (int)blockIdx.x;

    if (bid < npc) {
        // ---- per-chunk bucket histogram ----
        u32* cnt = smem;           // [NSB] (NSB <= 1024 guaranteed by host)
        int c = bid;
        for (int s = tid; s < NSB; s += 256) cnt[s] = 0;
        __syncthreads();
        int s0 = c * CHP, end = min(E, s0 + CHP);
        int nq = (end - s0) >> 2;  // host guarantees E%4==0
        const int4* d4p = (const int4*)(ei + (size_t)E + s0);
        for (int qi = tid; qi < nq; qi += 256) {
            int4 d4 = d4p[qi];
            atomicAdd(&cnt[d4.x >> NPB_SHIFT], 1u);
            atomicAdd(&cnt[d4.y >> NPB_SHIFT], 1u);
            atomicAdd(&cnt[d4.z >> NPB_SHIFT], 1u);
            atomicAdd(&cnt[d4.w >> NPB_SHIFT], 1u);
        }
        __syncthreads();
        for (int s = tid; s < NSB; s += 256) g1[(size_t)s * npc + c] = cnt[s];
        return;
    }

    // ---- PQ role ----
    float* sWTa = (float*)smem;            // [j][k] = W1[k][j]-W1[k+32][j]
    float* sWTb = (float*)smem + 2048;     // [j][k] = W1[k+32][j]
    for (int idx = tid; idx < 2048; idx += 256) {
        int j = idx >> 5, k = idx & 31;
        float a = W1[k * 64 + j];
        float b = W1[(k + 32) * 64 + j];
        sWTa[j * 32 + k] = a - b;
        sWTb[j * 32 + k] = b;
    }
    __syncthreads();

    int blk = bid - npc;
    int n = blk * 256 + tid;

    u32 pw[32], qw[32];
    if (n < N) {
        float xr[32];
        const float4* x4 = reinterpret_cast<const float4*>(x + (size_t)n * 32);
#pragma unroll
        for (int q = 0; q < 8; ++q) {
            float4 v = x4[q];
            xr[4 * q] = v.x; xr[4 * q + 1] = v.y; xr[4 * q + 2] = v.z; xr[4 * q + 3] = v.w;
        }
        for (int j0 = 0; j0 < 64; j0 += 4) {
            float pv[4], qv[4];
#pragma unroll
            for (int m = 0; m < 4; ++m) {
                int j = j0 + m;
                float a = b1[j], q = 0.f;
#pragma unroll
                for (int k = 0; k < 32; ++k) {
                    a = fmaf(xr[k], sWTa[j * 32 + k], a);
                    q = fmaf(xr[k], sWTb[j * 32 + k], q);
                }
                pv[m] = a; qv[m] = q;
            }
            pw[(j0 >> 1)]     = (u32)bf16rne(pv[0]) | ((u32)bf16rne(pv[1]) << 16);
            pw[(j0 >> 1) + 1] = (u32)bf16rne(pv[2]) | ((u32)bf16rne(pv[3]) << 16);
            qw[(j0 >> 1)]     = (u32)bf16rne(qv[0]) | ((u32)bf16rne(qv[1]) << 16);
            qw[(j0 >> 1) + 1] = (u32)bf16rne(qv[2]) | ((u32)bf16rne(qv[3]) << 16);
        }
    }
    __syncthreads();   // weights dead; smem re-used as staging

    u32* sP = smem;            // [64][33] padded
    u32* sQ = smem + 2112;
    for (int r = 0; r < 4; ++r) {
        if ((tid >> 6) == r && n < N) {
            int row = tid & 63;
#pragma unroll
            for (int i = 0; i < 32; ++i) {
                sP[row * 33 + i] = pw[i];
                sQ[row * 33 + i] = qw[i];
            }
        }
        __syncthreads();
        int nodebase = blk * 256 + r * 64;
        size_t wbase = (size_t)nodebase * 32;
        for (int w = tid; w < 2048; w += 256) {
            int node = nodebase + (w >> 5);
            if (node < N) {
                u32 v = sP[(w >> 5) * 33 + (w & 31)];
                u32 u = sQ[(w >> 5) * 33 + (w & 31)];
                Pb[wbase + w] = v;
                Qb[wbase + w] = u;
            }
        }
        __syncthreads();
    }
}

// ---------- partial scan, 2048 items/block (8/thread) + block-sum scan ----------
__global__ __launch_bounds__(256) void k_scan1(const u32* __restrict__ deg, u32* __restrict__ cursor,
                                               u32* __restrict__ bsum, int M) {
    __shared__ u32 sh[256];
    int t = threadIdx.x;
    int base = blockIdx.x * 2048 + t * 8;
    u32 v[8];
    if (base + 7 < M) {
        uint4 a = *reinterpret_cast<const uint4*>(deg + base);
        uint4 b = *reinterpret_cast<const uint4*>(deg + base + 4);
        v[0] = a.x; v[1] = a.y; v[2] = a.z; v[3] = a.w;
        v[4] = b.x; v[5] = b.y; v[6] = b.z; v[7] = b.w;
    } else {
#pragma unroll
        for (int i = 0; i < 8; ++i) v[i] = (base + i < M) ? deg[base + i] : 0;
    }
    u32 s = 0;
#pragma unroll
    for (int i = 0; i < 8; ++i) s += v[i];
    sh[t] = s; __syncthreads();
    u32 acc = s;
    for (int off = 1; off < 256; off <<= 1) {
        u32 add = (t >= off) ? sh[t - off] : 0;
        __syncthreads();
        acc += add; sh[t] = acc;
        __syncthreads();
    }
    u32 run = acc - s;
#pragma unroll
    for (int i = 0; i < 8; ++i) {
        if (base + i < M) cursor[base + i] = run;
        run += v[i];
    }
    if (t == 255) bsum[blockIdx.x] = acc;
}

__global__ __launch_bounds__(256) void k_scan2(const u32* __restrict__ bsum, u32* __restrict__ bsumX, int nb) {
    __shared__ u32 sh[256];
    int t = threadIdx.x;
    u32 v = (t < nb) ? bsum[t] : 0;
    sh[t] = v; __syncthreads();
    u32 acc = v;
    for (int off = 1; off < 256; off <<= 1) {
        u32 add = (t >= off) ? sh[t - off] : 0;
        __syncthreads();
        acc += add; sh[t] = acc;
        __syncthreads();
    }
    if (t < nb) bsumX[t] = acc - v;
}

// ---------- K_sp1: scatter u32 records into buckets (deterministic bases) ----------
// record: src (17b) | local (7b) << 17
__global__ __launch_bounds__(512) void k_sp1(const int* __restrict__ ei,
                                             const u32* __restrict__ g1cur, const u32* __restrict__ bsumX1,
                                             u32* __restrict__ sorted, int E, int NSB, int npc) {
    __shared__ u32 sb[1024], cnt[1024];
    int tid = threadIdx.x;
    int c = (int)blockIdx.x;
    for (int s = tid; s < NSB; s += 512) {
        size_t idx = (size_t)s * npc + c;
        sb[s] = g1cur[idx] + bsumX1[idx >> 11];
        cnt[s] = 0;
    }
    __syncthreads();
    int s0 = c * CHP, end = min(E, s0 + CHP);
    int nq = (end - s0) >> 2;
    const int4* d4p = (const int4*)(ei + (size_t)E + s0);
    const int4* s4p = (const int4*)(ei + s0);
    for (int qi = tid; qi < nq; qi += 512) {
        int4 d4 = d4p[qi];
        int4 s4 = s4p[qi];
        int dd[4] = {d4.x, d4.y, d4.z, d4.w};
        int ss[4] = {s4.x, s4.y, s4.z, s4.w};
#pragma unroll
        for (int u = 0; u < 4; ++u) {
            int s = dd[u] >> NPB_SHIFT;
            u32 r = atomicAdd(&cnt[s], 1u);
            sorted[sb[s] + r] = (u32)ss[u] | ((u32)(dd[u] & (NPB - 1)) << 17);
        }
    }
}

// ---------- K_bucket: 4 blocks x 256 threads per 128-node sort bucket ----------
// block (b, q) owns sub-bucket q (32 nodes): stream bucket records in 1024-segments,
// ballot-compact matching records into LDS queue, drain 16-edge MFMA tiles, 4 KB agg.
// A-frag (16x16x32 bf16): lane l holds A[row=l&15][k=(l>>4)*8 + j]
// C/D (m89-verified):     lane l, reg i -> D[row=(l>>4)*4+i][col=l&15]
__global__ __launch_bounds__(256) void k_bucket(
    const u32* __restrict__ Pb, const u32* __restrict__ Qb,
    const u32* __restrict__ sorted, const u32* __restrict__ g1cur, const u32* __restrict__ bsumX1,
    const float* __restrict__ W2, const float* __restrict__ b2,
    float* __restrict__ out, int E, int N, int NSB, int npc)
{
    __shared__ u32 queue[1024];     // 4 KB compacted records
    __shared__ u32 agg[32 * 32];    // 4 KB encoded-u32 max, 0 = "untouched"
    __shared__ u32 qc;
    int b = (int)blockIdx.x >> 2;
    int q = (int)blockIdx.x & 3;
    int tid = threadIdx.x;
    for (int i = tid; i < 1024; i += 256) agg[i] = 0u;

    int lane = tid & 63;
    int wid = tid >> 6;            // 0..3
    int n = lane & 15;
    int kc = lane >> 4;

    // W2 resident as 4 bf16 B-fragments
    short8v b00, b01, b10, b11;
#pragma unroll
    for (int j = 0; j < 8; ++j) {
        int k = kc * 8 + j;
        b00[j] = (short)bf16rne(W2[k * 32 + n]);
        b01[j] = (short)bf16rne(W2[(k + 32) * 32 + n]);
        b10[j] = (short)bf16rne(W2[k * 32 + n + 16]);
        b11[j] = (short)bf16rne(W2[(k + 32) * 32 + n + 16]);
    }

    size_t i0 = (size_t)b * npc;
    u32 start = g1cur[i0] + bsumX1[i0 >> 11];
    u32 bend;
    if (b + 1 < NSB) {
        size_t i1 = (size_t)(b + 1) * npc;
        bend = g1cur[i1] + bsumX1[i1 >> 11];
    } else {
        bend = (u32)E;
    }
    int nodebase = b << NPB_SHIFT;      // base node of the 128-bucket
    int subbase = nodebase + (q << 5);  // base node of this 32-sub-bucket

    __syncthreads();

    for (u32 seg = start; seg < bend; seg += 1024) {
        if (tid == 0) qc = 0;
        __syncthreads();

        // ---- fill: ballot-compact matching records into queue ----
        u32 idx = seg + tid;
#pragma unroll
        for (int it = 0; it < 4; ++it, idx += 256) {
            bool m = false;
            u32 rec = 0;
            if (idx < bend) {
                rec = sorted[idx];
                m = (int)((rec >> 22) & 3u) == q;     // local>>5
            }
            unsigned long long mask = __ballot(m);
            int prefix = __popcll(mask & ((1ull << (tid & 63)) - 1ull));
            int wcount = __popcll(mask);
            u32 base;
            if ((tid & 63) == 0) base = atomicAdd(&qc, (u32)wcount);
            base = __shfl(base, 0, 64);
            if (m) queue[base + prefix] = rec;
        }
        __syncthreads();

        // ---- drain: 16-edge MFMA tiles ----
        int cnt = (int)qc;
        int ntq = (cnt + 15) >> 4;
        for (int t = wid; t < ntq; t += 4) {
            int si = t * 16 + n;
            bool valid = si < cnt;
            u32 rec = queue[valid ? si : 0];
            int src = (int)(rec & 0x1FFFFu);
            int loc7 = (int)((rec >> 17) & 127u);
            int sub = loc7 & 31;
            int local = valid ? sub : -1;
            int prow = nodebase + (valid ? loc7 : 0);

            const u32* qr = Qb + (size_t)src * 32;
            const u32* pr = Pb + (size_t)prow * 32;
            uint4 qA0 = *(const uint4*)(qr + kc * 4);
            uint4 qA1 = *(const uint4*)(qr + 16 + kc * 4);
            uint4 pA0 = *(const uint4*)(pr + kc * 4);
            uint4 pA1 = *(const uint4*)(pr + 16 + kc * 4);

            u32 pa[4] = {pA0.x, pA0.y, pA0.z, pA0.w};
            u32 ph[4] = {pA1.x, pA1.y, pA1.z, pA1.w};
            u32 qa[4] = {qA0.x, qA0.y, qA0.z, qA0.w};
            u32 qh[4] = {qA1.x, qA1.y, qA1.z, qA1.w};

            u32x4 aw0, aw1;
#pragma unroll
            for (int u = 0; u < 4; ++u) {
                float l0 = fmaxf(bflo(pa[u]) + bflo(qa[u]), 0.f);
                float h0 = fmaxf(bfhi(pa[u]) + bfhi(qa[u]), 0.f);
                aw0[u] = cvtpk(l0, h0);
                float l1 = fmaxf(bflo(ph[u]) + bflo(qh[u]), 0.f);
                float h1 = fmaxf(bfhi(ph[u]) + bfhi(qh[u]), 0.f);
                aw1[u] = cvtpk(l1, h1);
            }
            short8v a0 = __builtin_bit_cast(short8v, aw0);
            short8v a1 = __builtin_bit_cast(short8v, aw1);

            f32x4 d0 = {0.f, 0.f, 0.f, 0.f};
            f32x4 d1 = {0.f, 0.f, 0.f, 0.f};
            d0 = __builtin_amdgcn_mfma_f32_16x16x32_bf16(a0, b00, d0, 0, 0, 0);
            d0 = __builtin_amdgcn_mfma_f32_16x16x32_bf16(a1, b01, d0, 0, 0, 0);
            d1 = __builtin_amdgcn_mfma_f32_16x16x32_bf16(a0, b10, d1, 0, 0, 0);
            d1 = __builtin_amdgcn_mfma_f32_16x16x32_bf16(a1, b11, d1, 0, 0, 0);

            // rows owned by this lane: r = kc*4 + i; row r's record lives in lane r
#pragma unroll
            for (int i = 0; i < 4; ++i) {
                int r = kc * 4 + i;
                int lr = __shfl(local, r, 64);
                if (lr >= 0) {
                    int sw = (lr & 1) << 4;
                    atomicMax(&agg[(lr << 5) + (n ^ sw)], enc_f32(d0[i]));
                    atomicMax(&agg[(lr << 5) + ((n + 16) ^ sw)], enc_f32(d1[i]));
                }
            }
        }
        __syncthreads();   // queue/qc reused next segment
    }

    // fused decode + b2 + empty->0; exclusive sub-bucket ownership -> plain coalesced store
    for (int i = tid; i < 1024; i += 256) {
        int local = i >> 5, c = i & 31;
        int node = subbase + local;
        if (node < N) {
            u32 u = agg[(local << 5) + (c ^ ((local & 1) << 4))];
            out[(size_t)node * 32 + c] = u ? (dec_f32(u) + b2[c]) : 0.f;
        }
    }
}

// ---------- fallback (round-1 style) ----------
__global__ __launch_bounds__(256) void fb_edge(const float* __restrict__ x, const int* __restrict__ ei,
                                               const float* __restrict__ W1, const float* __restrict__ b1,
                                               const float* __restrict__ W2, const float* __restrict__ b2,
                                               u32* __restrict__ out, int E) {
    int e = blockIdx.x * 256 + threadIdx.x;
    if (e >= E) return;
    int src = ei[e], dst = ei[E + e];
    float m[64];
    const float4* xi4 = reinterpret_cast<const float4*>(x + (size_t)dst * 32);
    const float4* xj4 = reinterpret_cast<const float4*>(x + (size_t)src * 32);
#pragma unroll
    for (int q = 0; q < 8; ++q) {
        float4 a = xi4[q], b = xj4[q];
        m[q * 4] = a.x; m[q * 4 + 1] = a.y; m[q * 4 + 2] = a.z; m[q * 4 + 3] = a.w;
        m[32 + q * 4] = b.x - a.x; m[32 + q * 4 + 1] = b.y - a.y;
        m[32 + q * 4 + 2] = b.z - a.z; m[32 + q * 4 + 3] = b.w - a.w;
    }
    float acc[32];
#pragma unroll
    for (int c = 0; c < 32; ++c) acc[c] = b2[c];
    for (int j = 0; j < 64; ++j) {
        float h = b1[j];
#pragma unroll
        for (int k = 0; k < 64; ++k) h = fmaf(m[k], W1[k * 64 + j], h);
        h = fmaxf(h, 0.0f);
#pragma unroll
        for (int c = 0; c < 32; ++c) acc[c] = fmaf(h, W2[j * 32 + c], acc[c]);
    }
    u32* o = out + (size_t)dst * 32;
#pragma unroll
    for (int c = 0; c < 32; ++c) atomicMax(o + c, enc_f32(acc[c]));
}
__global__ __launch_bounds__(256) void fb_decode(u32* __restrict__ buf, int n) {
    int i = blockIdx.x * 256 + threadIdx.x;
    if (i >= n) return;
    u32 u = buf[i];
    reinterpret_cast<float*>(buf)[i] = u ? dec_f32(u) : 0.f;
}

extern "C" void kernel_launch(void* const* d_in, const int* in_sizes, int n_in,
                              void* d_out, int out_size, void* d_ws, size_t ws_size,
                              hipStream_t stream) {
    const float* x  = (const float*)d_in[0];
    const int*   ei = (const int*)d_in[1];
    const float* W1 = (const float*)d_in[2];
    const float* b1 = (const float*)d_in[3];
    const float* W2 = (const float*)d_in[4];
    const float* b2 = (const float*)d_in[5];

    int N = in_sizes[0] / 32;
    int E = in_sizes[1] / 2;
    int NSB = (N + NPB - 1) >> NPB_SHIFT;       // 782 sort buckets of 128 nodes
    int npc = (E + CHP - 1) / CHP;              // 391 chunks
    int M1  = NSB * npc;                        // flat hist (305,762)
    int nb1 = (M1 + 2047) / 2048;               // 150 scan blocks

    // workspace layout (256B aligned)
    char* ws = (char*)d_ws;
    size_t off = 0;
    auto alloc = [&](size_t bytes) { char* p = ws + off; off += (bytes + 255) & ~(size_t)255; return p; };
    u32*   Pb     = (u32*)alloc((size_t)N * 32 * 4);
    u32*   Qb     = (u32*)alloc((size_t)N * 32 * 4);
    u32*   g1     = (u32*)alloc((size_t)M1 * 4);
    u32*   g1cur  = (u32*)alloc((size_t)M1 * 4);
    u32*   bsum1  = (u32*)alloc(256 * 4);
    u32*   bsumX1 = (u32*)alloc(256 * 4);
    u32*   sorted = (u32*)alloc((size_t)E * 4);
    // NSB<=1024 (sp1 LDS arrays), src fits 17b, E%4 for quad streams, M1 scan fits
    bool fits = (off <= ws_size) && (NSB <= 1024) && (N < (1 << 17)) &&
                ((E & 3) == 0) && (nb1 <= 256);

    if (!fits) {
        hipMemsetAsync(d_out, 0, (size_t)out_size * 4, stream);
        int be = (E + 255) / 256;
        fb_edge<<<be, 256, 0, stream>>>(x, ei, W1, b1, W2, b2, (u32*)d_out, E);
        fb_decode<<<(out_size + 255) / 256, 256, 0, stream>>>((u32*)d_out, out_size);
        return;
    }

    int pq_blocks = (N + 255) / 256;
    k_pq_hist<<<npc + pq_blocks, 256, 0, stream>>>(x, W1, b1, ei, Pb, Qb, g1, N, E, NSB, npc);

    k_scan1<<<nb1, 256, 0, stream>>>(g1, g1cur, bsum1, M1);
    k_scan2<<<1, 256, 0, stream>>>(bsum1, bsumX1, nb1);

    k_sp1<<<npc, 512, 0, stream>>>(ei, g1cur, bsumX1, sorted, E, NSB, npc);

    k_bucket<<<SUBQ * NSB, 256, 0, stream>>>(Pb, Qb, sorted, g1cur, bsumX1, W2, b2,
                                             (float*)d_out, E, N, NSB, npc);
}